// Round 3
// baseline (490.203 us; speedup 1.0000x reference)
//
#include <hip/hip_runtime.h>
#include <hip/hip_bf16.h>

typedef __hip_bfloat16 bf16;
typedef __attribute__((ext_vector_type(8))) short short8;
typedef __attribute__((ext_vector_type(4))) float f32x4;

#define MFMA16(A, B, C) __builtin_amdgcn_mfma_f32_16x16x32_bf16((A), (B), (C), 0, 0, 0)

// ---------------- prep: W fp32 -> frag-major bf16 in ws ----------------
__global__ __launch_bounds__(256) void prep_w(const float* __restrict__ wq,
                                              const float* __restrict__ wk,
                                              const float* __restrict__ wv,
                                              bf16* __restrict__ wsW)
{
    const int t = (int)blockIdx.x * 256 + (int)threadIdx.x;   // 0..24575
    const int lane = t & 63, kk = (t >> 6) & 7, mt = (t >> 9) & 15, proj = t >> 13;
    const float* W = (proj == 0) ? wq : ((proj == 1) ? wk : wv);
    const int row = mt * 16 + (lane & 15);
    const int col = kk * 32 + (lane >> 4) * 8;
    bf16* dst = wsW + (size_t)t * 8;
#pragma unroll
    for (int j = 0; j < 8; ++j) dst[j] = __float2bfloat16(W[row * 256 + col + j]);
}

__device__ __forceinline__ void proj_mfma(const short8 (&wf)[2][8], f32x4 (&acc)[2][4],
                                          const bf16 (*Xp)[264], int c15, int h)
{
#pragma unroll
    for (int nt = 0; nt < 4; ++nt)
#pragma unroll
        for (int kk = 0; kk < 8; ++kk) {
            const short8 bx = *(const short8*)&Xp[nt * 16 + c15][kk * 32 + h * 8];
            acc[0][nt] = MFMA16(wf[0][kk], bx, acc[0][nt]);
            acc[1][nt] = MFMA16(wf[1][kk], bx, acc[1][nt]);
        }
}

__global__ __launch_bounds__(512, 2)
void fused_sa(const float* __restrict__ x,
              const float* __restrict__ bq, const float* __restrict__ bk,
              const float* __restrict__ bv,
              const bf16* __restrict__ wsW,
              float* __restrict__ out)
{
    __shared__ __align__(16) bf16 Xs[2][64][264];   // double-buffered   67.6 KB
    __shared__ __align__(16) bf16 QL[8][9][264];    //                   38.0 KB
    __shared__ __align__(16) bf16 KL[8][9][264];    //                   38.0 KB
    __shared__ __align__(16) bf16 PL[8][8][8];      //                    1.0 KB
    bf16  (* const VL2)[257][8]  = (bf16 (*)[257][8])&QL[0][0][0];   // aliases QL
    float (* const OT)[16][8][8] = (float (*)[16][8][8])&KL[0][0][0]; // aliases KL (32 KB)

    const int tid = (int)threadIdx.x;
    const int l = tid & 63, w = tid >> 6;
    const int h = l >> 4, c15 = l & 15;

    // XCD-chunked swizzle over 256 persistent WGs
    const int bs = ((int)blockIdx.x & 7) * 32 + ((int)blockIdx.x >> 3);

    const short8* wsv = (const short8*)wsW;

    // biases resident (per-wave rows mt = w, w+8)
    float4 bbq[2], bbk[2], bbv[2];
#pragma unroll
    for (int mi = 0; mi < 2; ++mi) {
        const int mt = w + mi * 8;
        bbq[mi] = *(const float4*)&bq[mt * 16 + 4 * h];
        bbk[mi] = *(const float4*)&bk[mt * 16 + 4 * h];
        bbv[mi] = *(const float4*)&bv[mt * 16 + 4 * h];
    }

    const int p2 = (l & 3) * 2, chi = l >> 2;
    float2 xpre[16];

    // ---- stage tile 0 ----
    {
        const int g0 = bs * 8, b0 = g0 >> 9, p00 = (g0 & 511) * 8;
#pragma unroll
        for (int i = 0; i < 16; ++i) {
            const int c = i * 16 + chi;
            xpre[i] = *(const float2*)&x[((size_t)((b0 * 8 + w) * 256 + c)) * 4096 + p00 + p2];
        }
#pragma unroll
        for (int i = 0; i < 16; ++i) {
            const int c = i * 16 + chi;
            Xs[0][w * 8 + p2][c]     = __float2bfloat16(xpre[i].x);
            Xs[0][w * 8 + p2 + 1][c] = __float2bfloat16(xpre[i].y);
        }
    }

    for (int it = 0; it < 8; ++it) {
        const int g = bs * 8 + it, b = g >> 9, p0 = (g & 511) * 8, cur = it & 1;

        // ---- prefetch next tile's x into regs (latency hides under this tile) ----
        if (it < 7) {
            const int gn = g + 1, bn = gn >> 9, p0n = (gn & 511) * 8;
#pragma unroll
            for (int i = 0; i < 16; ++i) {
                const int c = i * 16 + chi;
                xpre[i] = *(const float2*)&x[((size_t)((bn * 8 + w) * 256 + c)) * 4096 + p0n + p2];
            }
        }

        // wfQ (L2-hot after round 1)
        short8 wfQ[2][8];
#pragma unroll
        for (int mi = 0; mi < 2; ++mi)
#pragma unroll
            for (int kk = 0; kk < 8; ++kk)
                wfQ[mi][kk] = wsv[((0 * 16 + w + 8 * mi) * 8 + kk) * 64 + l];

        __syncthreads();   // B1: Xs[cur] ready; prev tile's PV/OT reads done

        const int p = c15 & 7;
        // ---- Q projection ----
        {
            f32x4 acc[2][4] = {};
            proj_mfma(wfQ, acc, Xs[cur], c15, h);
            // issue wfK during Q epilogue
            short8 wfK[2][8];
#pragma unroll
            for (int mi = 0; mi < 2; ++mi)
#pragma unroll
                for (int kk = 0; kk < 8; ++kk)
                    wfK[mi][kk] = wsv[((1 * 16 + w + 8 * mi) * 8 + kk) * 64 + l];
#pragma unroll
            for (int mi = 0; mi < 2; ++mi) {
                const int mt = w + 8 * mi;
                const float bbv4[4] = {bbq[mi].x, bbq[mi].y, bbq[mi].z, bbq[mi].w};
#pragma unroll
                for (int nt = 0; nt < 4; ++nt) {
                    const int sp = 2 * nt + (c15 >> 3);
#pragma unroll
                    for (int r = 0; r < 4; ++r) {
                        const int ap = mt * 16 + 4 * h + r;
                        QL[p][ap >> 5][((ap & 31) << 3) | sp] =
                            __float2bfloat16(acc[mi][nt][r] + bbv4[r]);
                    }
                }
            }
            // ---- K projection ----
            f32x4 acck[2][4] = {};
            proj_mfma(wfK, acck, Xs[cur], c15, h);
#pragma unroll
            for (int mi = 0; mi < 2; ++mi) {
                const int mt = w + 8 * mi;
                const float bbv4[4] = {bbk[mi].x, bbk[mi].y, bbk[mi].z, bbk[mi].w};
#pragma unroll
                for (int nt = 0; nt < 4; ++nt) {
                    const int sp = 2 * nt + (c15 >> 3);
#pragma unroll
                    for (int r = 0; r < 4; ++r) {
                        const int ap = mt * 16 + 4 * h + r;
                        KL[p][ap & 7][(sp << 5) | (ap >> 3)] =
                            __float2bfloat16(acck[mi][nt][r] + bbv4[r]);
                    }
                }
            }
        }
        // wfV (issue before barrier; used after scores)
        short8 wfV[2][8];
#pragma unroll
        for (int mi = 0; mi < 2; ++mi)
#pragma unroll
            for (int kk = 0; kk < 8; ++kk)
                wfV[mi][kk] = wsv[((2 * 16 + w + 8 * mi) * 8 + kk) * 64 + l];

        __syncthreads();   // B2: QL, KL ready

        // ---- scores + softmax (waves 0-3) ----
        if (w < 4) {
            const int q = w;
            const int pxr = c15 >> 3, st = c15 & 7;
            f32x4 sacc = {0.f, 0.f, 0.f, 0.f};
#pragma unroll
            for (int kk = 0; kk < 8; ++kk) {
                const short8 qa = *(const short8*)&QL[2 * q + pxr][st][kk * 32 + h * 8];
                const short8 kb = *(const short8*)&KL[2 * q + pxr][st][kk * 32 + h * 8];
                sacc = MFMA16(qa, kb, sacc);
            }
            const bool valid = ((h >> 1) == pxr);
            const int px = 2 * q + (h >> 1);
#pragma unroll
            for (int r = 0; r < 4; ++r) {
                const float S = sacc[r] * 0.0625f;
                float m = S;
                m = fmaxf(m, __shfl_xor(m, 1));
                m = fmaxf(m, __shfl_xor(m, 2));
                m = fmaxf(m, __shfl_xor(m, 4));
                const float e = __expf(S - m);
                float sm = e;
                sm += __shfl_xor(sm, 1);
                sm += __shfl_xor(sm, 2);
                sm += __shfl_xor(sm, 4);
                if (valid) PL[px][4 * (h & 1) + r][st] = __float2bfloat16(e / sm);
            }
        }
        // ---- V projection (all waves) ----
        f32x4 vacc[2][4] = {};
        proj_mfma(wfV, vacc, Xs[cur], c15, h);
        __syncthreads();   // B3: scores done reading QL/KL; PL written

        // ---- V epilogue -> VL2 (aliases QL) ----
#pragma unroll
        for (int mi = 0; mi < 2; ++mi) {
            const int mt = w + 8 * mi;
            const float bbv4[4] = {bbv[mi].x, bbv[mi].y, bbv[mi].z, bbv[mi].w};
#pragma unroll
            for (int nt = 0; nt < 4; ++nt) {
                const int sp = 2 * nt + (c15 >> 3);
#pragma unroll
                for (int r = 0; r < 4; ++r) {
                    const int ap = mt * 16 + 4 * h + r;
                    VL2[p][((ap & 31) << 3) | sp][ap >> 5] =
                        __float2bfloat16(vacc[mi][nt][r] + bbv4[r]);
                }
            }
        }
        __syncthreads();   // B4: VL2, PL ready; KL (OT region) free

        // ---- PV -> per-wave OT transpose -> coalesced 32B stores ----
        const short8 zv = {0, 0, 0, 0, 0, 0, 0, 0};
#pragma unroll
        for (int ci = 0; ci < 2; ++ci) {
            const int ct = 2 * w + ci;
#pragma unroll
            for (int g2 = 0; g2 < 2; ++g2)
#pragma unroll
                for (int T = 0; T < 2; ++T) {
                    short8 pa = *(const short8*)&PL[4 * g2 + 2 * T + (c15 >> 3)][c15 & 7][0];
                    if (h != 2 * T + (c15 >> 3)) pa = zv;
                    const short8 vb = *(const short8*)&VL2[4 * g2 + h][16 * ct + c15][0];
                    f32x4 pacc = {0.f, 0.f, 0.f, 0.f};
                    pacc = MFMA16(pa, vb, pacc);
                    const int pix = 4 * g2 + 2 * T + (h >> 1);
#pragma unroll
                    for (int r = 0; r < 4; ++r)
                        OT[w][(c15 >> 3) * 8 + 4 * (h & 1) + r][c15 & 7][pix] = pacc[r];
                }
            // read back coalesced rows, 32B per lane-row (compiler inserts lgkmcnt)
#pragma unroll
            for (int q = 0; q < 2; ++q) {
                const int f  = 2 * l + q;           // 0..127
                const int cbs = f >> 3, s2 = f & 7;
                const int cb = cbs >> 3, s = cbs & 7;
                const int a2 = (s << 5) | (4 * w + 2 * ci + cb);
                const float4 v0 = *(const float4*)&OT[w][cbs][s2][0];
                const float4 v1 = *(const float4*)&OT[w][cbs][s2][4];
                float* op = &out[((size_t)((b * 8 + s2) * 256 + a2)) * 4096 + p0];
                *(float4*)&op[0] = v0;
                *(float4*)&op[4] = v1;
            }
        }

        // ---- write next tile's Xs (other buffer; no barrier needed) ----
        if (it < 7) {
#pragma unroll
            for (int i = 0; i < 16; ++i) {
                const int c = i * 16 + chi;
                Xs[cur ^ 1][w * 8 + p2][c]     = __float2bfloat16(xpre[i].x);
                Xs[cur ^ 1][w * 8 + p2 + 1][c] = __float2bfloat16(xpre[i].y);
            }
        }
    }
}

extern "C" void kernel_launch(void* const* d_in, const int* in_sizes, int n_in,
                              void* d_out, int out_size, void* d_ws, size_t ws_size,
                              hipStream_t stream) {
    (void)in_sizes; (void)n_in; (void)out_size; (void)ws_size;
    const float* x  = (const float*)d_in[0];
    const float* wq = (const float*)d_in[1];
    const float* bq = (const float*)d_in[2];
    const float* wk = (const float*)d_in[3];
    const float* bk = (const float*)d_in[4];
    const float* wv = (const float*)d_in[5];
    const float* bv = (const float*)d_in[6];
    float* out = (float*)d_out;
    bf16* wsW  = (bf16*)d_ws;   // 393,216 bytes

    hipLaunchKernelGGL(prep_w, dim3(96), dim3(256), 0, stream, wq, wk, wv, wsW);
    hipLaunchKernelGGL(fused_sa, dim3(256), dim3(512), 0, stream,
                       x, bq, bk, bv, wsW, out);
}

// Round 4
// 278.610 us; speedup vs baseline: 1.7595x; 1.7595x over previous
//
#include <hip/hip_runtime.h>
#include <hip/hip_bf16.h>

typedef __hip_bfloat16 bf16;
typedef __attribute__((ext_vector_type(8))) short short8;
typedef __attribute__((ext_vector_type(4))) float f32x4;

#define MFMA16(A, B, C) __builtin_amdgcn_mfma_f32_16x16x32_bf16((A), (B), (C), 0, 0, 0)

// ---------------- prep: W fp32 -> frag-major bf16 in ws ----------------
__global__ __launch_bounds__(256) void prep_w(const float* __restrict__ wq,
                                              const float* __restrict__ wk,
                                              const float* __restrict__ wv,
                                              bf16* __restrict__ wsW)
{
    const int t = (int)blockIdx.x * 256 + (int)threadIdx.x;   // 0..24575
    const int lane = t & 63, kk = (t >> 6) & 7, mt = (t >> 9) & 15, proj = t >> 13;
    const float* W = (proj == 0) ? wq : ((proj == 1) ? wk : wv);
    const int row = mt * 16 + (lane & 15);
    const int col = kk * 32 + (lane >> 4) * 8;
    bf16* dst = wsW + (size_t)t * 8;
#pragma unroll
    for (int j = 0; j < 8; ++j) dst[j] = __float2bfloat16(W[row * 256 + col + j]);
}

__global__ __launch_bounds__(1024, 4)
void fused_sa(const float* __restrict__ x,
              const float* __restrict__ bq, const float* __restrict__ bk,
              const float* __restrict__ bv,
              const bf16* __restrict__ wsW,
              float* __restrict__ out)
{
    // Region map (bytes):
    //   [0,      33792)  Xs[64][264] bf16      ; later VL2[8][257][8] bf16 (32896)
    //   [33792,  71808)  QL[8][9][264] bf16    ; later OT (with KL region)
    //   [71808, 109824)  KL[8][9][264] bf16    ; OT[16][16][8][8] f32 = 65536 over QL+KL
    //   [109824,110848)  PL[8][8][8] bf16
    __shared__ __align__(16) char SMEM[110848];
    bf16  (* const Xs)[264]       = (bf16 (*)[264])&SMEM[0];
    bf16  (* const QL)[9][264]    = (bf16 (*)[9][264])&SMEM[33792];
    bf16  (* const KL)[9][264]    = (bf16 (*)[9][264])&SMEM[71808];
    bf16  (* const PL)[8][8]      = (bf16 (*)[8][8])&SMEM[109824];
    bf16  (* const VL2)[257][8]   = (bf16 (*)[257][8])&SMEM[0];
    float (* const OT)[16][8][8]  = (float (*)[16][8][8])&SMEM[33792];

    const int tid = (int)threadIdx.x;
    const int l = tid & 63, w = tid >> 6;          // 16 waves
    const int h = l >> 4, c15 = l & 15;

    // XCD-chunked swizzle over 256 WGs; tile g = it*256 + bs keeps the 256
    // concurrent WGs on ADJACENT p-tiles every iteration (L2 line merging).
    const int bs = ((int)blockIdx.x & 7) * 32 + ((int)blockIdx.x >> 3);

    const short8* wsv = (const short8*)wsW;

    // staging coords: wave stages s' = w&7, c-half = (w>>3)*128
    const int sp_st = w & 7, chb = (w >> 3) * 128;
    const int p2 = (l & 3) * 2, chi = l >> 2;

    float2 xpre[8];
    {
        const int p00 = bs * 8;                    // it=0: g=bs, b=0
#pragma unroll
        for (int i = 0; i < 8; ++i) {
            const int c = chb + i * 16 + chi;
            xpre[i] = *(const float2*)&x[((size_t)(sp_st * 256 + c)) * 4096 + p00 + p2];
        }
    }

    for (int it = 0; it < 8; ++it) {
        const int g = it * 256 + bs, b = g >> 9, p0 = (g & 511) * 8;

        // wfQ loads first (vmem latency overlaps the ds writes below)
        short8 wf[8];
#pragma unroll
        for (int kk = 0; kk < 8; ++kk)
            wf[kk] = wsv[((0 * 16 + w) * 8 + kk) * 64 + l];

        // write Xs from prefetched regs
#pragma unroll
        for (int i = 0; i < 8; ++i) {
            const int c = chb + i * 16 + chi;
            Xs[sp_st * 8 + p2][c]     = __float2bfloat16(xpre[i].x);
            Xs[sp_st * 8 + p2 + 1][c] = __float2bfloat16(xpre[i].y);
        }
        // prefetch next tile's x (hides under this tile's compute)
        if (it < 7) {
            const int gn = g + 256, bn = gn >> 9, p0n = (gn & 511) * 8;
#pragma unroll
            for (int i = 0; i < 8; ++i) {
                const int c = chb + i * 16 + chi;
                xpre[i] = *(const float2*)&x[((size_t)((bn * 8 + sp_st) * 256 + c)) * 4096 + p0n + p2];
            }
        }
        __syncthreads();   // B1: Xs ready; prev iter's OT readback done

        const int p = c15 & 7;

        // ---- Q projection (wave owns m-tile w, all 4 n-tiles) ----
        {
            f32x4 acc[4] = {};
#pragma unroll
            for (int nt = 0; nt < 4; ++nt)
#pragma unroll
                for (int kk = 0; kk < 8; ++kk) {
                    const short8 bx = *(const short8*)&Xs[nt * 16 + c15][kk * 32 + h * 8];
                    acc[nt] = MFMA16(wf[kk], bx, acc[nt]);
                }
            const float4 bb = *(const float4*)&bq[w * 16 + 4 * h];
            const float bbv4[4] = {bb.x, bb.y, bb.z, bb.w};
#pragma unroll
            for (int nt = 0; nt < 4; ++nt) {
                const int sp = 2 * nt + (c15 >> 3);
#pragma unroll
                for (int r = 0; r < 4; ++r) {
                    const int ap = w * 16 + 4 * h + r;
                    QL[p][ap >> 5][((ap & 31) << 3) | sp] =
                        __float2bfloat16(acc[nt][r] + bbv4[r]);
                }
            }
        }
        // ---- K projection ----
        {
#pragma unroll
            for (int kk = 0; kk < 8; ++kk)
                wf[kk] = wsv[((1 * 16 + w) * 8 + kk) * 64 + l];
            f32x4 acc[4] = {};
#pragma unroll
            for (int nt = 0; nt < 4; ++nt)
#pragma unroll
                for (int kk = 0; kk < 8; ++kk) {
                    const short8 bx = *(const short8*)&Xs[nt * 16 + c15][kk * 32 + h * 8];
                    acc[nt] = MFMA16(wf[kk], bx, acc[nt]);
                }
            const float4 bb = *(const float4*)&bk[w * 16 + 4 * h];
            const float bbv4[4] = {bb.x, bb.y, bb.z, bb.w};
#pragma unroll
            for (int nt = 0; nt < 4; ++nt) {
                const int sp = 2 * nt + (c15 >> 3);
#pragma unroll
                for (int r = 0; r < 4; ++r) {
                    const int ap = w * 16 + 4 * h + r;
                    KL[p][ap & 7][(sp << 5) | (ap >> 3)] =
                        __float2bfloat16(acc[nt][r] + bbv4[r]);
                }
            }
        }
        // ---- V projection (result held in regs through scores) ----
        f32x4 vacc[4] = {};
        {
#pragma unroll
            for (int kk = 0; kk < 8; ++kk)
                wf[kk] = wsv[((2 * 16 + w) * 8 + kk) * 64 + l];
#pragma unroll
            for (int nt = 0; nt < 4; ++nt)
#pragma unroll
                for (int kk = 0; kk < 8; ++kk) {
                    const short8 bx = *(const short8*)&Xs[nt * 16 + c15][kk * 32 + h * 8];
                    vacc[nt] = MFMA16(wf[kk], bx, vacc[nt]);
                }
        }
        __syncthreads();   // B2: QL/KL ready; Xs reads done (Xs now dead)

        // ---- scores + softmax (waves 0-3, one per SIMD) ----
        if (w < 4) {
            const int q = w;
            const int pxr = c15 >> 3, st = c15 & 7;
            f32x4 sacc = {0.f, 0.f, 0.f, 0.f};
#pragma unroll
            for (int kk = 0; kk < 8; ++kk) {
                const short8 qa = *(const short8*)&QL[2 * q + pxr][st][kk * 32 + h * 8];
                const short8 kb = *(const short8*)&KL[2 * q + pxr][st][kk * 32 + h * 8];
                sacc = MFMA16(qa, kb, sacc);
            }
            const bool valid = ((h >> 1) == pxr);
            const int px = 2 * q + (h >> 1);
#pragma unroll
            for (int r = 0; r < 4; ++r) {
                const float S = sacc[r] * 0.0625f;
                float m = S;
                m = fmaxf(m, __shfl_xor(m, 1));
                m = fmaxf(m, __shfl_xor(m, 2));
                m = fmaxf(m, __shfl_xor(m, 4));
                const float e = __expf(S - m);
                float sm = e;
                sm += __shfl_xor(sm, 1);
                sm += __shfl_xor(sm, 2);
                sm += __shfl_xor(sm, 4);
                if (valid) PL[px][4 * (h & 1) + r][st] = __float2bfloat16(e / sm);
            }
        }
        // ---- V epilogue -> VL2 (aliases dead Xs; overlaps scores) ----
        {
            const float4 bb = *(const float4*)&bv[w * 16 + 4 * h];
            const float bbv4[4] = {bb.x, bb.y, bb.z, bb.w};
#pragma unroll
            for (int nt = 0; nt < 4; ++nt) {
                const int sp = 2 * nt + (c15 >> 3);
#pragma unroll
                for (int r = 0; r < 4; ++r) {
                    const int ap = w * 16 + 4 * h + r;
                    VL2[p][((ap & 31) << 3) | sp][ap >> 5] =
                        __float2bfloat16(vacc[nt][r] + bbv4[r]);
                }
            }
        }
        __syncthreads();   // B3: VL2 + PL ready; QL/KL dead (OT region free)

        // ---- PV (wave owns a-column-tile ct = w) -> OT -> coalesced stores ----
        const short8 zv = {0, 0, 0, 0, 0, 0, 0, 0};
#pragma unroll
        for (int g2 = 0; g2 < 2; ++g2)
#pragma unroll
            for (int T = 0; T < 2; ++T) {
                short8 pa = *(const short8*)&PL[4 * g2 + 2 * T + (c15 >> 3)][c15 & 7][0];
                if (h != 2 * T + (c15 >> 3)) pa = zv;
                const short8 vb = *(const short8*)&VL2[4 * g2 + h][16 * w + c15][0];
                f32x4 pacc = {0.f, 0.f, 0.f, 0.f};
                pacc = MFMA16(pa, vb, pacc);
                const int pix = 4 * g2 + 2 * T + (h >> 1);
#pragma unroll
                for (int r = 0; r < 4; ++r)
                    OT[w][(c15 >> 3) * 8 + 4 * (h & 1) + r][c15 & 7][pix] = pacc[r];
            }
        // per-wave OT readback (own region only) + 32B stores; drain under B4
#pragma unroll
        for (int q2 = 0; q2 < 2; ++q2) {
            const int f = 2 * l + q2;              // 0..127
            const int cbs = f >> 3, s2 = f & 7;
            const int cb = cbs >> 3, s = cbs & 7;
            const int a2 = (s << 5) | (2 * w + cb);
            const float4 v0 = *(const float4*)&OT[w][cbs][s2][0];
            const float4 v1 = *(const float4*)&OT[w][cbs][s2][4];
            float* op = &out[((size_t)((b * 8 + s2) * 256 + a2)) * 4096 + p0];
            *(float4*)&op[0] = v0;
            *(float4*)&op[4] = v1;
        }
        __syncthreads();   // B4: VL2 reads done -> Xs writable next iter
    }
}

extern "C" void kernel_launch(void* const* d_in, const int* in_sizes, int n_in,
                              void* d_out, int out_size, void* d_ws, size_t ws_size,
                              hipStream_t stream) {
    (void)in_sizes; (void)n_in; (void)out_size; (void)ws_size;
    const float* x  = (const float*)d_in[0];
    const float* wq = (const float*)d_in[1];
    const float* bq = (const float*)d_in[2];
    const float* wk = (const float*)d_in[3];
    const float* bk = (const float*)d_in[4];
    const float* wv = (const float*)d_in[5];
    const float* bv = (const float*)d_in[6];
    float* out = (float*)d_out;
    bf16* wsW  = (bf16*)d_ws;   // 393,216 bytes

    hipLaunchKernelGGL(prep_w, dim3(96), dim3(256), 0, stream, wq, wk, wv, wsW);
    hipLaunchKernelGGL(fused_sa, dim3(256), dim3(1024), 0, stream,
                       x, bq, bk, bv, wsW, out);
}

// Round 5
// 272.927 us; speedup vs baseline: 1.7961x; 1.0208x over previous
//
#include <hip/hip_runtime.h>
#include <hip/hip_bf16.h>

typedef __hip_bfloat16 bf16;
typedef __attribute__((ext_vector_type(8))) short short8;
typedef __attribute__((ext_vector_type(4))) float f32x4;

#define MFMA16(A, B, C) __builtin_amdgcn_mfma_f32_16x16x32_bf16((A), (B), (C), 0, 0, 0)

// ---------------- prep: W fp32 -> frag-major bf16 in ws ----------------
__global__ __launch_bounds__(256) void prep_w(const float* __restrict__ wq,
                                              const float* __restrict__ wk,
                                              const float* __restrict__ wv,
                                              bf16* __restrict__ wsW)
{
    const int t = (int)blockIdx.x * 256 + (int)threadIdx.x;   // 0..24575
    const int lane = t & 63, kk = (t >> 6) & 7, mt = (t >> 9) & 15, proj = t >> 13;
    const float* W = (proj == 0) ? wq : ((proj == 1) ? wk : wv);
    const int row = mt * 16 + (lane & 15);
    const int col = kk * 32 + (lane >> 4) * 8;
    bf16* dst = wsW + (size_t)t * 8;
#pragma unroll
    for (int j = 0; j < 8; ++j) dst[j] = __float2bfloat16(W[row * 256 + col + j]);
}

// ---------------- kernel A: projections -> Qw/Kw/Vw (bf16) ----------------
__device__ __forceinline__ void proj_mfma(const short8 (&wf)[2][8], f32x4 (&acc)[2][4],
                                          const bf16 (*Xp)[264], int c15, int h)
{
#pragma unroll
    for (int nt = 0; nt < 4; ++nt)
#pragma unroll
        for (int kk = 0; kk < 8; ++kk) {
            const short8 bx = *(const short8*)&Xp[nt * 16 + c15][kk * 32 + h * 8];
            acc[0][nt] = MFMA16(wf[0][kk], bx, acc[0][nt]);
            acc[1][nt] = MFMA16(wf[1][kk], bx, acc[1][nt]);
        }
}

__global__ __launch_bounds__(512, 4)
void projA(const float* __restrict__ x,
           const float* __restrict__ bq, const float* __restrict__ bk,
           const float* __restrict__ bv,
           const bf16* __restrict__ wsW,
           bf16* __restrict__ qw, bf16* __restrict__ kw, bf16* __restrict__ vw,
           int b_base, int nwg)
{
    __shared__ __align__(16) bf16 Xs[64][264];     // 33792 B
    __shared__ __align__(16) bf16 bounce[16384];   // 32768 B  (one tensor tile)

    const int tid = (int)threadIdx.x;
    const int l = tid & 63, w = tid >> 6, h = l >> 4, c15 = l & 15;
    const int chunk = nwg >> 3;
    const int wg = ((int)blockIdx.x & 7) * chunk + ((int)blockIdx.x >> 3);
    const int b = b_base + (wg >> 9), p0 = (wg & 511) * 8;
    const short8* wsv = (const short8*)wsW;

    // ---- stage X -> Xs bf16 ----
    const int p2 = (l & 3) * 2, chi = l >> 2;
    {
        float2 xv[16];
#pragma unroll
        for (int i = 0; i < 16; ++i) {
            const int c = i * 16 + chi;
            xv[i] = *(const float2*)&x[((size_t)((b * 8 + w) * 256 + c)) * 4096 + p0 + p2];
        }
#pragma unroll
        for (int i = 0; i < 16; ++i) {
            const int c = i * 16 + chi;
            Xs[w * 8 + p2][c]     = __float2bfloat16(xv[i].x);
            Xs[w * 8 + p2 + 1][c] = __float2bfloat16(xv[i].y);
        }
    }

    const int p = c15 & 7;
    short8 wf[2][8];
#pragma unroll
    for (int mi = 0; mi < 2; ++mi)
#pragma unroll
        for (int kk = 0; kk < 8; ++kk)
            wf[mi][kk] = wsv[((0 * 16 + w + 8 * mi) * 8 + kk) * 64 + l];

    __syncthreads();   // B1: Xs ready

    // ---- Q projection -> bounce ----
    {
        f32x4 acc[2][4] = {};
        proj_mfma(wf, acc, Xs, c15, h);
#pragma unroll
        for (int mi = 0; mi < 2; ++mi)
#pragma unroll
            for (int kk = 0; kk < 8; ++kk)
                wf[mi][kk] = wsv[((1 * 16 + w + 8 * mi) * 8 + kk) * 64 + l];  // wfK
#pragma unroll
        for (int mi = 0; mi < 2; ++mi) {
            const int mt = w + 8 * mi;
            const float4 bb = *(const float4*)&bq[mt * 16 + 4 * h];
            const float bv4[4] = {bb.x, bb.y, bb.z, bb.w};
#pragma unroll
            for (int nt = 0; nt < 4; ++nt) {
                const int sp = 2 * nt + (c15 >> 3);
#pragma unroll
                for (int r = 0; r < 4; ++r) {
                    const int ap = mt * 16 + 4 * h + r;
                    bounce[((p * 8 + (ap >> 5)) << 8) + ((ap & 31) << 3) + sp] =
                        __float2bfloat16(acc[mi][nt][r] + bv4[r]);
                }
            }
        }
    }
    __syncthreads();   // B2: Q in bounce

    // ---- flush Q + K projection ----
    {
        const short8* bs = (const short8*)bounce;
        short8* dq = (short8*)(qw + (size_t)wg * 16384);
#pragma unroll
        for (int i = 0; i < 4; ++i) dq[i * 512 + tid] = bs[i * 512 + tid];
    }
    f32x4 acck[2][4] = {};
    proj_mfma(wf, acck, Xs, c15, h);
#pragma unroll
    for (int mi = 0; mi < 2; ++mi)
#pragma unroll
        for (int kk = 0; kk < 8; ++kk)
            wf[mi][kk] = wsv[((2 * 16 + w + 8 * mi) * 8 + kk) * 64 + l];      // wfV
    __syncthreads();   // B3: flushQ readers done

    // ---- K epilogue -> bounce ----
#pragma unroll
    for (int mi = 0; mi < 2; ++mi) {
        const int mt = w + 8 * mi;
        const float4 bb = *(const float4*)&bk[mt * 16 + 4 * h];
        const float bv4[4] = {bb.x, bb.y, bb.z, bb.w};
#pragma unroll
        for (int nt = 0; nt < 4; ++nt) {
            const int sp = 2 * nt + (c15 >> 3);
#pragma unroll
            for (int r = 0; r < 4; ++r) {
                const int ap = mt * 16 + 4 * h + r;
                bounce[((p * 8 + (ap & 7)) << 8) + (sp << 5) + (ap >> 3)] =
                    __float2bfloat16(acck[mi][nt][r] + bv4[r]);
            }
        }
    }
    __syncthreads();   // B4: K in bounce

    // ---- flush K + V projection ----
    {
        const short8* bs = (const short8*)bounce;
        short8* dk = (short8*)(kw + (size_t)wg * 16384);
#pragma unroll
        for (int i = 0; i < 4; ++i) dk[i * 512 + tid] = bs[i * 512 + tid];
    }
    f32x4 accv[2][4] = {};
    proj_mfma(wf, accv, Xs, c15, h);
    __syncthreads();   // B5: flushK readers done

    // ---- V epilogue -> bounce ([p][a][t]) ----
#pragma unroll
    for (int mi = 0; mi < 2; ++mi) {
        const int mt = w + 8 * mi;
        const float4 bb = *(const float4*)&bv[mt * 16 + 4 * h];
        const float bv4[4] = {bb.x, bb.y, bb.z, bb.w};
#pragma unroll
        for (int nt = 0; nt < 4; ++nt) {
            const int sp = 2 * nt + (c15 >> 3);
#pragma unroll
            for (int r = 0; r < 4; ++r) {
                const int ap = mt * 16 + 4 * h + r;
                bounce[(((p << 8) + ((ap & 31) << 3) + sp) << 3) + (ap >> 5)] =
                    __float2bfloat16(accv[mi][nt][r] + bv4[r]);
            }
        }
    }
    __syncthreads();   // B6: V in bounce

    {
        const short8* bs = (const short8*)bounce;
        short8* dv = (short8*)(vw + (size_t)wg * 16384);
#pragma unroll
        for (int i = 0; i < 4; ++i) dv[i * 512 + tid] = bs[i * 512 + tid];
    }
}

// ---------------- kernel B: attention (QKVw -> out) ----------------
__global__ __launch_bounds__(256, 4)
void attnB(const bf16* __restrict__ qw, const bf16* __restrict__ kw,
           const bf16* __restrict__ vw, float* __restrict__ out,
           int b_base, int nwg)
{
    __shared__ __align__(16) bf16 PL[16][9][8];   // [px][s][t] probs, padded rows

    const int tid = (int)threadIdx.x;
    const int l = tid & 63, w = tid >> 6, h = l >> 4, c15 = l & 15;
    const int chunk = nwg >> 3;
    const int wg = ((int)blockIdx.x & 7) * chunk + ((int)blockIdx.x >> 3);
    const int b = b_base + (wg >> 8), pt16 = wg & 255;
    const int lt8 = (wg >> 8) * 512 + pt16 * 2;     // local tile8 base
    const size_t p16 = (size_t)pt16 * 16;

    // ---- scores + softmax (wave w owns pixel-pair tiles 2w, 2w+1) ----
    const int pxr = c15 >> 3, st = c15 & 7;
#pragma unroll
    for (int ti = 0; ti < 2; ++ti) {
        const int tau = w * 2 + ti;
        const int px = 2 * tau + pxr;
        const size_t tb = (size_t)(lt8 + (px >> 3)) * 16384 + (size_t)(((px & 7) * 8 + st) * 256);
        const short8* Qb = (const short8*)(qw + tb);
        const short8* Kb = (const short8*)(kw + tb);
        f32x4 sacc = {0.f, 0.f, 0.f, 0.f};
#pragma unroll
        for (int kk = 0; kk < 8; ++kk)
            sacc = MFMA16(Qb[kk * 4 + h], Kb[kk * 4 + h], sacc);
        const bool valid = ((h >> 1) == pxr);
        const int pxo = 2 * tau + (h >> 1);
#pragma unroll
        for (int r = 0; r < 4; ++r) {
            const float S = sacc[r] * 0.0625f;
            float m = S;
            m = fmaxf(m, __shfl_xor(m, 1));
            m = fmaxf(m, __shfl_xor(m, 2));
            m = fmaxf(m, __shfl_xor(m, 4));
            const float e = __expf(S - m);
            float sm = e;
            sm += __shfl_xor(sm, 1);
            sm += __shfl_xor(sm, 2);
            sm += __shfl_xor(sm, 4);
            if (valid) PL[pxo][4 * (h & 1) + r][st] = __float2bfloat16(e / sm);
        }
    }
    __syncthreads();

    // ---- PV: D rows = (s-half, 4 px), cols = a; pacc = 4 consecutive px ----
    const int pxl = c15 & 3, sl = c15 >> 2;
    const short8 zv = {0, 0, 0, 0, 0, 0, 0, 0};
#pragma unroll
    for (int sg = 0; sg < 2; ++sg) {
        short8 pa[4];
#pragma unroll
        for (int q = 0; q < 4; ++q) {
            const short8 t = *(const short8*)&PL[q * 4 + pxl][sg * 4 + sl][0];
            pa[q] = (h == pxl) ? t : zv;
        }
        const int s = sg * 4 + h;
#pragma unroll
        for (int ci = 0; ci < 4; ++ci) {
            const int a = (w * 4 + ci) * 16 + c15;
            const int s2 = a & 7, a2 = (s << 5) | (a >> 3);
            float* orow = &out[((size_t)((b * 8 + s2) * 256 + a2)) * 4096 + p16];
#pragma unroll
            for (int q = 0; q < 4; ++q) {
                const int px = q * 4 + h;
                const size_t vo = (size_t)(lt8 + (px >> 3)) * 16384 +
                                  (size_t)((((px & 7) << 8) + a) << 3);
                const short8 vb = *(const short8*)(vw + vo);
                f32x4 pacc = {0.f, 0.f, 0.f, 0.f};
                pacc = MFMA16(pa[q], vb, pacc);
                *(f32x4*)&orow[q * 4] = pacc;   // 16B store, 4 consecutive pixels
            }
        }
    }
}

extern "C" void kernel_launch(void* const* d_in, const int* in_sizes, int n_in,
                              void* d_out, int out_size, void* d_ws, size_t ws_size,
                              hipStream_t stream) {
    (void)in_sizes; (void)n_in; (void)out_size;
    const float* x  = (const float*)d_in[0];
    const float* wq = (const float*)d_in[1];
    const float* bq = (const float*)d_in[2];
    const float* wk = (const float*)d_in[3];
    const float* bk = (const float*)d_in[4];
    const float* wv = (const float*)d_in[5];
    const float* bv = (const float*)d_in[6];
    float* out = (float*)d_out;

    bf16* wsW = (bf16*)d_ws;                 // 196608 el = 384 KB
    bf16* qwp = wsW + 196608;

    int nb = 4;                              // batches per A/B pass (ws-adaptive)
    while (nb > 1 && ws_size < 2ull * (196608ull + 3ull * (size_t)nb * 512 * 16384))
        nb >>= 1;
    const size_t span = (size_t)nb * 512 * 16384;
    bf16* kwp = qwp + span;
    bf16* vwp = kwp + span;

    hipLaunchKernelGGL(prep_w, dim3(96), dim3(256), 0, stream, wq, wk, wv, wsW);
    for (int b0 = 0; b0 < 4; b0 += nb) {
        hipLaunchKernelGGL(projA, dim3(nb * 512), dim3(512), 0, stream,
                           x, bq, bk, bv, wsW, qwp, kwp, vwp, b0, nb * 512);
        hipLaunchKernelGGL(attnB, dim3(nb * 256), dim3(256), 0, stream,
                           qwp, kwp, vwp, out, b0, nb * 256);
    }
}